// Round 4
// baseline (155.265 us; speedup 1.0000x reference)
//
#include <hip/hip_runtime.h>
#include <hip/hip_bf16.h>

// out = x @ W.T + 2*b ; M=N=K=4096, fp32 in/out.
// Round 4: 256x256 8-phase bf16 GEMM with 32x32x16 MFMA (2382 TF ceiling vs
// 2075 for 16x16), T2 granule-XOR swizzle (conflict-free, verified 0 in R3),
// T3/T4 counted vmcnt(4), T5 setprio, T1 XCD swizzle. sched_barrier removed.
// Pass 1 converts X,W to bf16 in d_ws (single merged kernel).

typedef short bf16x8 __attribute__((ext_vector_type(8)));
typedef short s16x4  __attribute__((ext_vector_type(4)));
typedef short s16x8  __attribute__((ext_vector_type(8)));
typedef float f32x4  __attribute__((ext_vector_type(4)));
typedef float f32x16 __attribute__((ext_vector_type(16)));

constexpr int MDIM = 4096, NDIM = 4096, KDIM = 4096;

typedef const __attribute__((address_space(1))) void* gas_t;
typedef __attribute__((address_space(3))) void*       las_t;

__device__ __forceinline__ short f2bf(float f) {
    __hip_bfloat16 h = __float2bfloat16(f);   // RNE
    short s; __builtin_memcpy(&s, &h, 2); return s;
}

// ---------------- pass 1: fp32 -> bf16 convert (X and W in one launch) ----------------
__global__ __launch_bounds__(256)
void cvt2_f32_bf16(const float* __restrict__ inA, const float* __restrict__ inB,
                   short* __restrict__ outA, short* __restrict__ outB, int n8each) {
    int idx    = blockIdx.x * blockDim.x + threadIdx.x;
    int stride = gridDim.x * blockDim.x;
    for (int i = idx; i < 2 * n8each; i += stride) {
        const f32x4* in4 = (i < n8each) ? (const f32x4*)inA : (const f32x4*)inB;
        s16x8*      out8 = (i < n8each) ? (s16x8*)outA      : (s16x8*)outB;
        int j = (i < n8each) ? i : i - n8each;
        f32x4 a = in4[2 * j];
        f32x4 b = in4[2 * j + 1];
        s16x8 o = { f2bf(a[0]), f2bf(a[1]), f2bf(a[2]), f2bf(a[3]),
                    f2bf(b[0]), f2bf(b[1]), f2bf(b[2]), f2bf(b[3]) };
        out8[j] = o;
    }
}

// ---------------- pass 2: 256x256 8-phase bf16 GEMM, 32x32x16 ----------------
constexpr int BM = 256, BN = 256, BK = 64;
constexpr int NT  = KDIM / BK;   // 64 K-tiles
constexpr int ASZ = BM * BK;     // 16384 shorts (32 KiB) per A buffer
constexpr int BSZ = BN * BK;

// one phase: A-fragment ds_reads (4x b128) + staging + barrier + 8 MFMA_32x32x16
template <int MF, class StageFn>
__device__ __forceinline__ void phase32(const short* Ab, int rA, const int (&ck)[4],
                                        bf16x8 (&bf)[2][4], f32x16 (&acc)[4][2],
                                        StageFn&& stage) {
    bf16x8 af[4];
    const short* p = &Ab[(rA + MF * 32) * BK];
    #pragma unroll
    for (int s = 0; s < 4; ++s)
        af[s] = *(const bf16x8*)(p + ck[s]);
    stage();
    __builtin_amdgcn_s_barrier();
    __builtin_amdgcn_s_setprio(1);
    #pragma unroll
    for (int nf = 0; nf < 2; ++nf)
        #pragma unroll
        for (int s = 0; s < 4; ++s)
            acc[MF][nf] = __builtin_amdgcn_mfma_f32_32x32x16_bf16(
                              af[s], bf[nf][s], acc[MF][nf], 0, 0, 0);
    __builtin_amdgcn_s_setprio(0);
}

__global__ __launch_bounds__(512, 2)
void gemm_bf16_256(const short* __restrict__ Xb, const short* __restrict__ Wb,
                   const float* __restrict__ Bv, float* __restrict__ Out)
{
    __shared__ short lds[2 * ASZ + 2 * BSZ];   // 128 KiB

    const int tid  = threadIdx.x;
    const int lane = tid & 63;
    const int wid  = tid >> 6;          // 0..7
    const int wr   = wid >> 2;          // 0..1 (M)
    const int wc   = wid & 3;           // 0..3 (N)

    // T1: XCD-chunked block swizzle (nwg=256, divisible by 8 -> bijective)
    const int bid = blockIdx.x;
    const int lin = (bid & 7) * 32 + (bid >> 3);
    const int tm0 = (lin >> 4) * BM;
    const int tn0 = (lin & 15) * BN;

    // ---- staging: linear LDS dest, inverse-swizzled global source ----
    // lane l -> row l>>3 within 8-row segment, granule (l&7)^(row&7)
    const int srow = lane >> 3;
    const int sgrn = (lane & 7) ^ srow;
    const short* aSrc[2][2];
    const short* bSrc[2][2];
    int dOff[2][2];
    #pragma unroll
    for (int h = 0; h < 2; ++h) {
        #pragma unroll
        for (int j = 0; j < 2; ++j) {
            const int r = h * 128 + (2 * wid + j) * 8;   // segment base row (mult of 8)
            aSrc[h][j] = Xb + (size_t)(tm0 + r + srow) * KDIM + sgrn * 8;
            bSrc[h][j] = Wb + (size_t)(tn0 + r + srow) * KDIM + sgrn * 8;
            dOff[h][j] = r * BK;
        }
    }
    auto stageA = [&](int kt, int h) {
        short* dst = (short*)&lds[(kt & 1) * ASZ];
        __builtin_amdgcn_global_load_lds((gas_t)(aSrc[h][0] + (size_t)kt * BK),
                                         (las_t)(dst + dOff[h][0]), 16, 0, 0);
        __builtin_amdgcn_global_load_lds((gas_t)(aSrc[h][1] + (size_t)kt * BK),
                                         (las_t)(dst + dOff[h][1]), 16, 0, 0);
    };
    auto stageB = [&](int kt, int h) {
        short* dst = (short*)&lds[2 * ASZ + (kt & 1) * BSZ];
        __builtin_amdgcn_global_load_lds((gas_t)(bSrc[h][0] + (size_t)kt * BK),
                                         (las_t)(dst + dOff[h][0]), 16, 0, 0);
        __builtin_amdgcn_global_load_lds((gas_t)(bSrc[h][1] + (size_t)kt * BK),
                                         (las_t)(dst + dOff[h][1]), 16, 0, 0);
    };

    // ---- fragment addressing (32x32x16, swizzled) ----
    // A/B lane layout: row/col = lane&31 ; k = (lane>>5)*8 + [0..7]
    // k-step s granule = 2s + (lane>>5) ; swizzle ^= (row&7) = (lane&7)
    const int l31 = lane & 31;
    const int g2  = lane >> 5;
    int ck[4];
    #pragma unroll
    for (int s = 0; s < 4; ++s)
        ck[s] = ((2 * s + g2) ^ (lane & 7)) * 8;   // element offset within row
    const int rA = wr * 128 + l31;
    const int rB = wc * 64  + l31;

    f32x16 acc[4][2] = {};

    // ---- prologue: stage (0).B, (0).A, (1).B ; drain (0) ----
    stageB(0, 0); stageB(0, 1); stageA(0, 0); stageA(0, 1); stageB(1, 0); stageB(1, 1);
    asm volatile("s_waitcnt vmcnt(4)" ::: "memory");   // (0) complete; (1).B in flight
    __builtin_amdgcn_s_barrier();

    // ---- main loop: 4 phases per K-tile ----
    // ledger: enter tile t with 4 outstanding ((t+1).B); +8 issued during t;
    // vmcnt(4) at end drains (t+1).A,B ; (t+2).B stays in flight across barrier.
    for (int t = 0; t < NT; ++t) {
        const short* Ab = (const short*)&lds[(t & 1) * ASZ];
        const short* Bb = (const short*)&lds[2 * ASZ + (t & 1) * BSZ];

        // phase 0: all B frags (8 reads) + A frag 0 ; stage (t+1).A0
        bf16x8 bf[2][4];
        #pragma unroll
        for (int nf = 0; nf < 2; ++nf) {
            const short* p = &Bb[(rB + nf * 32) * BK];
            #pragma unroll
            for (int s = 0; s < 4; ++s)
                bf[nf][s] = *(const bf16x8*)(p + ck[s]);
        }
        phase32<0>(Ab, rA, ck, bf, acc, [&] { if (t + 1 < NT) stageA(t + 1, 0); });
        __builtin_amdgcn_s_barrier();
        phase32<1>(Ab, rA, ck, bf, acc, [&] { if (t + 1 < NT) stageA(t + 1, 1); });
        __builtin_amdgcn_s_barrier();
        phase32<2>(Ab, rA, ck, bf, acc, [&] { if (t + 2 < NT) stageB(t + 2, 0); });
        __builtin_amdgcn_s_barrier();
        phase32<3>(Ab, rA, ck, bf, acc, [&] { if (t + 2 < NT) stageB(t + 2, 1); });
        if (t < NT - 2)       { asm volatile("s_waitcnt vmcnt(4)" ::: "memory"); }
        else if (t == NT - 2) { asm volatile("s_waitcnt vmcnt(0)" ::: "memory"); }
        __builtin_amdgcn_s_barrier();
    }

    // ---- epilogue: + 2*bias, fp32 store (32-lane x 4B = 128B segments) ----
    float bb[2];
    #pragma unroll
    for (int nf = 0; nf < 2; ++nf)
        bb[nf] = 2.0f * Bv[tn0 + wc * 64 + nf * 32 + l31];

    #pragma unroll
    for (int mf = 0; mf < 4; ++mf) {
        #pragma unroll
        for (int reg = 0; reg < 16; ++reg) {
            const int row = tm0 + wr * 128 + mf * 32
                          + (reg & 3) + 8 * (reg >> 2) + 4 * g2;
            float* orow = Out + (size_t)row * NDIM + tn0 + wc * 64 + l31;
            #pragma unroll
            for (int nf = 0; nf < 2; ++nf)
                orow[nf * 32] = acc[mf][nf][reg] + bb[nf];
        }
    }
}

// ---------------- fallback: fp32 reg-staged (if ws too small) ----------------
constexpr int FBM = 128, FBN = 128, FBK = 32, LDT = FBK + 8;
__global__ __launch_bounds__(256)
void gemm_xwt_bias2(const float* __restrict__ X, const float* __restrict__ W,
                    const float* __restrict__ Bv, float* __restrict__ Out)
{
    __shared__ short As[FBM * LDT];
    __shared__ short Bs[FBN * LDT];
    const int tid  = threadIdx.x;
    const int lane = tid & 63;
    const int wid  = tid >> 6;
    const int wr   = wid >> 1;
    const int wc   = wid & 1;
    const int tm0  = blockIdx.y * FBM;
    const int tn0  = blockIdx.x * FBN;
    const int srow = tid >> 3;
    const int scol = (tid & 7) * 4;
    const int g    = lane >> 4;
    const int r16  = lane & 15;
    f32x4 acc[4][4] = {};
    const float* xg = X + (size_t)(tm0 + srow) * KDIM + scol;
    const float* wg = W + (size_t)(tn0 + srow) * KDIM + scol;
    for (int k0 = 0; k0 < KDIM; k0 += FBK) {
        #pragma unroll
        for (int i = 0; i < 4; ++i) {
            const int row = srow + 32 * i;
            f32x4 av = *(const f32x4*)(xg + (size_t)(32 * i) * KDIM + k0);
            f32x4 bv = *(const f32x4*)(wg + (size_t)(32 * i) * KDIM + k0);
            s16x4 pa = { f2bf(av[0]), f2bf(av[1]), f2bf(av[2]), f2bf(av[3]) };
            s16x4 pb = { f2bf(bv[0]), f2bf(bv[1]), f2bf(bv[2]), f2bf(bv[3]) };
            *(s16x4*)&As[row * LDT + scol] = pa;
            *(s16x4*)&Bs[row * LDT + scol] = pb;
        }
        __syncthreads();
        bf16x8 af[4], bfr[4];
        #pragma unroll
        for (int mi = 0; mi < 4; ++mi)
            af[mi] = *(const bf16x8*)&As[(wr * 64 + mi * 16 + r16) * LDT + g * 8];
        #pragma unroll
        for (int ni = 0; ni < 4; ++ni)
            bfr[ni] = *(const bf16x8*)&Bs[(wc * 64 + ni * 16 + r16) * LDT + g * 8];
        #pragma unroll
        for (int mi = 0; mi < 4; ++mi)
            #pragma unroll
            for (int ni = 0; ni < 4; ++ni)
                acc[mi][ni] = __builtin_amdgcn_mfma_f32_16x16x32_bf16(
                                  af[mi], bfr[ni], acc[mi][ni], 0, 0, 0);
        __syncthreads();
    }
    float bb[4];
    #pragma unroll
    for (int ni = 0; ni < 4; ++ni)
        bb[ni] = 2.0f * Bv[tn0 + wc * 64 + ni * 16 + r16];
    #pragma unroll
    for (int mi = 0; mi < 4; ++mi)
        #pragma unroll
        for (int r = 0; r < 4; ++r) {
            const int row = tm0 + wr * 64 + mi * 16 + g * 4 + r;
            float* orow = Out + (size_t)row * NDIM + tn0 + wc * 64 + r16;
            #pragma unroll
            for (int ni = 0; ni < 4; ++ni)
                orow[ni * 16] = acc[mi][ni][r] + bb[ni];
        }
}

extern "C" void kernel_launch(void* const* d_in, const int* in_sizes, int n_in,
                              void* d_out, int out_size, void* d_ws, size_t ws_size,
                              hipStream_t stream) {
    const float* X  = (const float*)d_in[0];
    const float* W  = (const float*)d_in[1];
    const float* Bv = (const float*)d_in[2];
    float* Out = (float*)d_out;

    const size_t nElem = (size_t)MDIM * KDIM;
    const size_t need  = 2 * nElem * sizeof(short);   // 67.1 MB

    if (ws_size >= need) {
        short* Xb = (short*)d_ws;
        short* Wb = Xb + nElem;
        const int n8 = (int)(nElem / 8);
        cvt2_f32_bf16<<<4096, 256, 0, stream>>>(X, W, Xb, Wb, n8);
        gemm_bf16_256<<<dim3(256), 512, 0, stream>>>(Xb, Wb, Bv, Out);
    } else {
        dim3 grid(NDIM / FBN, MDIM / FBM);
        gemm_xwt_bias2<<<grid, 256, 0, stream>>>(X, W, Bv, Out);
    }
}

// Round 5
// 140.586 us; speedup vs baseline: 1.1044x; 1.1044x over previous
//
#include <hip/hip_runtime.h>
#include <hip/hip_bf16.h>
#include <utility>

// out = x @ W.T + 2*b ; M=N=K=4096, fp32 in/out.
// Round 5: revert to R3's 16x16x32 8-phase kernel (124us GEMM, 0 bank conflicts);
// add 2-tile unroll so LDS buffer parities are compile-time; merged cvt kernel.
// (R4's 32x32x16 variant regressed: granule-XOR swizzle is conflict-free for the
//  16x16 fragment read pattern but 4-way-conflicts for the 32x32 pattern.)

typedef short bf16x8 __attribute__((ext_vector_type(8)));
typedef short s16x4  __attribute__((ext_vector_type(4)));
typedef short s16x8  __attribute__((ext_vector_type(8)));
typedef float f32x4  __attribute__((ext_vector_type(4)));

constexpr int MDIM = 4096, NDIM = 4096, KDIM = 4096;

typedef const __attribute__((address_space(1))) void* gas_t;
typedef __attribute__((address_space(3))) void*       las_t;

__device__ __forceinline__ short f2bf(float f) {
    __hip_bfloat16 h = __float2bfloat16(f);   // RNE
    short s; __builtin_memcpy(&s, &h, 2); return s;
}

// ---------------- pass 1: fp32 -> bf16 convert (X and W, one launch) ----------------
__global__ __launch_bounds__(256)
void cvt2_f32_bf16(const float* __restrict__ inA, const float* __restrict__ inB,
                   short* __restrict__ outA, short* __restrict__ outB, int n8each) {
    int idx    = blockIdx.x * blockDim.x + threadIdx.x;
    int stride = gridDim.x * blockDim.x;
    for (int i = idx; i < 2 * n8each; i += stride) {
        const f32x4* in4 = (i < n8each) ? (const f32x4*)inA : (const f32x4*)inB;
        s16x8*      out8 = (i < n8each) ? (s16x8*)outA      : (s16x8*)outB;
        int j = (i < n8each) ? i : i - n8each;
        f32x4 a = in4[2 * j];
        f32x4 b = in4[2 * j + 1];
        s16x8 o = { f2bf(a[0]), f2bf(a[1]), f2bf(a[2]), f2bf(a[3]),
                    f2bf(b[0]), f2bf(b[1]), f2bf(b[2]), f2bf(b[3]) };
        out8[j] = o;
    }
}

// ---------------- pass 2: 256x256 8-phase bf16 GEMM (16x16x32) ----------------
constexpr int BM = 256, BN = 256, BK = 64;
constexpr int NT  = KDIM / BK;   // 64 K-tiles
constexpr int ASZ = BM * BK;     // 16384 shorts (32 KiB) per A buffer
constexpr int BSZ = BN * BK;

// one MFMA quadrant: A-quad ds_reads + staging + barrier + 16 MFMA
template <int Q, class StageFn>
__device__ __forceinline__ void phase(const short* Ab, int rA, int c0, int c1,
                                      bf16x8 (&bf)[4][2], f32x4 (&acc)[8][4],
                                      StageFn&& stage) {
    bf16x8 af[2][2];
    #pragma unroll
    for (int m = 0; m < 2; ++m) {
        const short* p = &Ab[(rA + Q * 32 + m * 16) * BK];
        af[m][0] = *(const bf16x8*)(p + c0);
        af[m][1] = *(const bf16x8*)(p + c1);
    }
    stage();
    __builtin_amdgcn_s_barrier();
    __builtin_amdgcn_s_setprio(1);
    #pragma unroll
    for (int m = 0; m < 2; ++m)
        #pragma unroll
        for (int ni = 0; ni < 4; ++ni)
            #pragma unroll
            for (int kk = 0; kk < 2; ++kk)
                acc[Q * 2 + m][ni] = __builtin_amdgcn_mfma_f32_16x16x32_bf16(
                    af[m][kk], bf[ni][kk], acc[Q * 2 + m][ni], 0, 0, 0);
    __builtin_amdgcn_s_setprio(0);
}

__global__ __launch_bounds__(512, 2)
void gemm_bf16_256(const short* __restrict__ Xb, const short* __restrict__ Wb,
                   const float* __restrict__ Bv, float* __restrict__ Out)
{
    __shared__ short lds[2 * ASZ + 2 * BSZ];   // 128 KiB

    const int tid  = threadIdx.x;
    const int lane = tid & 63;
    const int wid  = tid >> 6;          // 0..7
    const int wr   = wid >> 2;          // 0..1 (M)
    const int wc   = wid & 3;           // 0..3 (N)

    // T1: XCD-chunked block swizzle (nwg=256, divisible by 8 -> bijective)
    const int bid = blockIdx.x;
    const int lin = (bid & 7) * 32 + (bid >> 3);
    const int tm0 = (lin >> 4) * BM;
    const int tn0 = (lin & 15) * BN;

    // ---- staging: linear LDS dest, inverse-swizzled global source ----
    // lane l -> row l>>3 within 8-row segment, granule (l&7)^(row&7)
    const int srow = lane >> 3;
    const int sgrn = (lane & 7) ^ srow;
    const short* aSrc[2][2];
    const short* bSrc[2][2];
    int dOff[2][2];
    #pragma unroll
    for (int h = 0; h < 2; ++h) {
        #pragma unroll
        for (int j = 0; j < 2; ++j) {
            const int r = h * 128 + (2 * wid + j) * 8;   // segment base row (mult of 8)
            aSrc[h][j] = Xb + (size_t)(tm0 + r + srow) * KDIM + sgrn * 8;
            bSrc[h][j] = Wb + (size_t)(tn0 + r + srow) * KDIM + sgrn * 8;
            dOff[h][j] = r * BK;
        }
    }

    // ---- fragment read addressing (swizzled; m89-verified 16x16x32 layout) ----
    const int g   = lane >> 4;          // k-group 0..3 ; D-row group
    const int r16 = lane & 15;          // frag row ; D col
    const int c0  = ((0 + g) ^ (r16 & 7)) * 8;   // kk=0 granule (elements)
    const int c1  = ((4 + g) ^ (r16 & 7)) * 8;   // kk=1
    const int rA  = wr * 128 + r16;
    const int rB  = wc * 64  + r16;

    f32x4 acc[8][4] = {};

    // tile body, PAR = t&1 compile-time (static LDS bases / staging dests)
    auto tile_body = [&](auto par_ic, int t) {
        constexpr int PAR = decltype(par_ic)::value;
        const short* Ab = (const short*)&lds[PAR * ASZ];
        const short* Bb = (const short*)&lds[2 * ASZ + PAR * BSZ];
        short* dstA = (short*)&lds[(PAR ^ 1) * ASZ];           // A(t+1)
        short* dstB = (short*)&lds[2 * ASZ + PAR * BSZ];       // B(t+2)

        auto stageA = [&](int kt, int h) {
            __builtin_amdgcn_global_load_lds((gas_t)(aSrc[h][0] + (size_t)kt * BK),
                                             (las_t)(dstA + dOff[h][0]), 16, 0, 0);
            __builtin_amdgcn_global_load_lds((gas_t)(aSrc[h][1] + (size_t)kt * BK),
                                             (las_t)(dstA + dOff[h][1]), 16, 0, 0);
        };
        auto stageB = [&](int kt, int h) {
            __builtin_amdgcn_global_load_lds((gas_t)(bSrc[h][0] + (size_t)kt * BK),
                                             (las_t)(dstB + dOff[h][0]), 16, 0, 0);
            __builtin_amdgcn_global_load_lds((gas_t)(bSrc[h][1] + (size_t)kt * BK),
                                             (las_t)(dstB + dOff[h][1]), 16, 0, 0);
        };

        // phase 0: all B frags (8 reads) + A quad0 ; stage (t+1).A0
        bf16x8 bf[4][2];
        #pragma unroll
        for (int ni = 0; ni < 4; ++ni) {
            const short* p = &Bb[(rB + ni * 16) * BK];
            bf[ni][0] = *(const bf16x8*)(p + c0);
            bf[ni][1] = *(const bf16x8*)(p + c1);
        }
        phase<0>(Ab, rA, c0, c1, bf, acc, [&] { if (t + 1 < NT) stageA(t + 1, 0); });
        __builtin_amdgcn_s_barrier();
        phase<1>(Ab, rA, c0, c1, bf, acc, [&] { if (t + 1 < NT) stageA(t + 1, 1); });
        __builtin_amdgcn_s_barrier();
        phase<2>(Ab, rA, c0, c1, bf, acc, [&] { if (t + 2 < NT) stageB(t + 2, 0); });
        __builtin_amdgcn_s_barrier();
        phase<3>(Ab, rA, c0, c1, bf, acc, [&] { if (t + 2 < NT) stageB(t + 2, 1); });
        // ledger: enter tile t with 4 outstanding ((t+1).B); +8 issued during t;
        // vmcnt(4) drains (t+1).A,B ; (t+2).B stays in flight across barrier.
        if (t < NT - 2)       { asm volatile("s_waitcnt vmcnt(4)" ::: "memory"); }
        else if (t == NT - 2) { asm volatile("s_waitcnt vmcnt(0)" ::: "memory"); }
        __builtin_amdgcn_s_barrier();
    };

    // ---- prologue: stage (0).B, (0).A, (1).B ; drain (0) ----
    {
        short* dA0 = (short*)&lds[0];
        short* dB0 = (short*)&lds[2 * ASZ];
        short* dB1 = (short*)&lds[2 * ASZ + BSZ];
        #pragma unroll
        for (int h = 0; h < 2; ++h) {
            __builtin_amdgcn_global_load_lds((gas_t)bSrc[h][0], (las_t)(dB0 + dOff[h][0]), 16, 0, 0);
            __builtin_amdgcn_global_load_lds((gas_t)bSrc[h][1], (las_t)(dB0 + dOff[h][1]), 16, 0, 0);
        }
        #pragma unroll
        for (int h = 0; h < 2; ++h) {
            __builtin_amdgcn_global_load_lds((gas_t)aSrc[h][0], (las_t)(dA0 + dOff[h][0]), 16, 0, 0);
            __builtin_amdgcn_global_load_lds((gas_t)aSrc[h][1], (las_t)(dA0 + dOff[h][1]), 16, 0, 0);
        }
        #pragma unroll
        for (int h = 0; h < 2; ++h) {
            __builtin_amdgcn_global_load_lds((gas_t)(bSrc[h][0] + BK), (las_t)(dB1 + dOff[h][0]), 16, 0, 0);
            __builtin_amdgcn_global_load_lds((gas_t)(bSrc[h][1] + BK), (las_t)(dB1 + dOff[h][1]), 16, 0, 0);
        }
        asm volatile("s_waitcnt vmcnt(4)" ::: "memory");   // (0) complete; (1).B in flight
        __builtin_amdgcn_s_barrier();
    }

    // ---- main loop: 2 K-tiles per iteration, static parities ----
    for (int t = 0; t < NT; t += 2) {
        tile_body(std::integral_constant<int, 0>{}, t);
        tile_body(std::integral_constant<int, 1>{}, t + 1);
    }

    // ---- epilogue: + 2*bias, fp32 store ----
    float bb[4];
    #pragma unroll
    for (int ni = 0; ni < 4; ++ni)
        bb[ni] = 2.0f * Bv[tn0 + wc * 64 + ni * 16 + r16];

    #pragma unroll
    for (int mi = 0; mi < 8; ++mi) {
        #pragma unroll
        for (int r = 0; r < 4; ++r) {
            const int row = tm0 + wr * 128 + mi * 16 + g * 4 + r;
            float* orow = Out + (size_t)row * NDIM + tn0 + wc * 64 + r16;
            #pragma unroll
            for (int ni = 0; ni < 4; ++ni)
                orow[ni * 16] = acc[mi][ni][r] + bb[ni];
        }
    }
}

// ---------------- fallback: fp32 reg-staged (if ws too small) ----------------
constexpr int FBM = 128, FBN = 128, FBK = 32, LDT = FBK + 8;
__global__ __launch_bounds__(256)
void gemm_xwt_bias2(const float* __restrict__ X, const float* __restrict__ W,
                    const float* __restrict__ Bv, float* __restrict__ Out)
{
    __shared__ short As[FBM * LDT];
    __shared__ short Bs[FBN * LDT];
    const int tid  = threadIdx.x;
    const int lane = tid & 63;
    const int wid  = tid >> 6;
    const int wr   = wid >> 1;
    const int wc   = wid & 1;
    const int tm0  = blockIdx.y * FBM;
    const int tn0  = blockIdx.x * FBN;
    const int srow = tid >> 3;
    const int scol = (tid & 7) * 4;
    const int g    = lane >> 4;
    const int r16  = lane & 15;
    f32x4 acc[4][4] = {};
    const float* xg = X + (size_t)(tm0 + srow) * KDIM + scol;
    const float* wg = W + (size_t)(tn0 + srow) * KDIM + scol;
    for (int k0 = 0; k0 < KDIM; k0 += FBK) {
        #pragma unroll
        for (int i = 0; i < 4; ++i) {
            const int row = srow + 32 * i;
            f32x4 av = *(const f32x4*)(xg + (size_t)(32 * i) * KDIM + k0);
            f32x4 bv = *(const f32x4*)(wg + (size_t)(32 * i) * KDIM + k0);
            s16x4 pa = { f2bf(av[0]), f2bf(av[1]), f2bf(av[2]), f2bf(av[3]) };
            s16x4 pb = { f2bf(bv[0]), f2bf(bv[1]), f2bf(bv[2]), f2bf(bv[3]) };
            *(s16x4*)&As[row * LDT + scol] = pa;
            *(s16x4*)&Bs[row * LDT + scol] = pb;
        }
        __syncthreads();
        bf16x8 af[4], bfr[4];
        #pragma unroll
        for (int mi = 0; mi < 4; ++mi)
            af[mi] = *(const bf16x8*)&As[(wr * 64 + mi * 16 + r16) * LDT + g * 8];
        #pragma unroll
        for (int ni = 0; ni < 4; ++ni)
            bfr[ni] = *(const bf16x8*)&Bs[(wc * 64 + ni * 16 + r16) * LDT + g * 8];
        #pragma unroll
        for (int mi = 0; mi < 4; ++mi)
            #pragma unroll
            for (int ni = 0; ni < 4; ++ni)
                acc[mi][ni] = __builtin_amdgcn_mfma_f32_16x16x32_bf16(
                                  af[mi], bfr[ni], acc[mi][ni], 0, 0, 0);
        __syncthreads();
    }
    float bb[4];
    #pragma unroll
    for (int ni = 0; ni < 4; ++ni)
        bb[ni] = 2.0f * Bv[tn0 + wc * 64 + ni * 16 + r16];
    #pragma unroll
    for (int mi = 0; mi < 4; ++mi)
        #pragma unroll
        for (int r = 0; r < 4; ++r) {
            const int row = tm0 + wr * 64 + mi * 16 + g * 4 + r;
            float* orow = Out + (size_t)row * NDIM + tn0 + wc * 64 + r16;
            #pragma unroll
            for (int ni = 0; ni < 4; ++ni)
                orow[ni * 16] = acc[mi][ni][r] + bb[ni];
        }
}

extern "C" void kernel_launch(void* const* d_in, const int* in_sizes, int n_in,
                              void* d_out, int out_size, void* d_ws, size_t ws_size,
                              hipStream_t stream) {
    const float* X  = (const float*)d_in[0];
    const float* W  = (const float*)d_in[1];
    const float* Bv = (const float*)d_in[2];
    float* Out = (float*)d_out;

    const size_t nElem = (size_t)MDIM * KDIM;
    const size_t need  = 2 * nElem * sizeof(short);   // 67.1 MB

    if (ws_size >= need) {
        short* Xb = (short*)d_ws;
        short* Wb = Xb + nElem;
        const int n8 = (int)(nElem / 8);
        cvt2_f32_bf16<<<4096, 256, 0, stream>>>(X, W, Xb, Wb, n8);
        gemm_bf16_256<<<dim3(256), 512, 0, stream>>>(Xb, Wb, Bv, Out);
    } else {
        dim3 grid(NDIM / FBN, MDIM / FBM);
        gemm_xwt_bias2<<<grid, 256, 0, stream>>>(X, W, Bv, Out);
    }
}